// Round 3
// baseline (2150.455 us; speedup 1.0000x reference)
//
#include <hip/hip_runtime.h>
#include <hip/hip_bf16.h>
#include <math.h>

typedef __hip_bfloat16 bf16;
#define DEVI __device__ __forceinline__
static DEVI float b2f(bf16 v) { return __bfloat162float(v); }
static DEVI float scrub(float v) { return (v - v == 0.f) ? v : 0.f; }

constexpr int SLICE = 64 * 64 * 192;           // per-b elements = 786432

// ws layout (float offsets). Total 64,755,812 floats = 259,023,248 B (~247 MiB)
constexpr size_t O_XH   = 0;          // 25165824
constexpr size_t O_SI   = 25165824;   // 25165824
constexpr size_t O_ZB   = 50331648;   // bf16 z (25165824 elems = 12582912 slots)
constexpr size_t O_KMAP = 62914560;   // 786432
constexpr size_t O_FREQ = 63700992;   // 786432 (converted fp32 freq_embed)
constexpr size_t O_E64  = 64487424;   // 8192 (4096 float2)
constexpr size_t O_DM   = 64495616;   // 4096
constexpr size_t O_DT   = 64499712;   // 4096
constexpr size_t O_WT   = 64503808;   // 36864
constexpr size_t O_POOL = 64540672;   // 6144
constexpr size_t O_SEL  = 64546816;   // 32
constexpr size_t O_FLAG = 64546848;   // 32 (flag int + pad)
constexpr size_t O_W    = 64546880;   // 208932 packed fp32 weights
constexpr size_t WS_NEEDED_BYTES = (size_t)64755812 * 4;

// packed-weight offsets (relative to ws base)
constexpr size_t W_GN   = O_W + 0;      // 96
constexpr size_t W_DWW  = O_W + 96;     // 1728
constexpr size_t W_DWB  = O_W + 1824;   // 192
constexpr size_t W_LINW = O_W + 2016;   // 73728
constexpr size_t W_LINB = O_W + 75744;  // 384
constexpr size_t W_P1W  = O_W + 76128;  // 49152
constexpr size_t W_P1B  = O_W + 125280; // 256
constexpr size_t W_G1   = O_W + 125536; // 256
constexpr size_t W_B1   = O_W + 125792; // 256
constexpr size_t W_P2W  = O_W + 126048; // 8192
constexpr size_t W_P2B  = O_W + 134240; // 32
constexpr size_t W_G2   = O_W + 134272; // 32
constexpr size_t W_B2   = O_W + 134304; // 32
constexpr size_t W_P3W  = O_W + 134336; // 96
constexpr size_t W_P3B  = O_W + 134432; // 4 (3 used)
constexpr size_t W_TOKW = O_W + 134436; // 36864
constexpr size_t W_TOKB = O_W + 171300; // 192
constexpr size_t W_LNG  = O_W + 171492; // 192
constexpr size_t W_LNB  = O_W + 171684; // 192
constexpr size_t W_OUTW = O_W + 171876; // 36864
constexpr size_t W_OUTB = O_W + 208740; // 192

struct CvtArgs {
  const void* src[22];
  int n[22];
  long long off[22];   // float offset into ws
};

// ----------------------------------------------------------------------------
// dtype sniff: bf16 array -> ~64/64 sane uint16 exponents; fp32 -> ~40/64
// flag: 0 = bf16 inputs, 1 = fp32 inputs
// ----------------------------------------------------------------------------
__global__ void sniff_kernel(const unsigned short* xu, int* flag) {
  __shared__ int cnt;
  if (threadIdx.x == 0) cnt = 0;
  __syncthreads();
  unsigned short u = xu[threadIdx.x];
  int e = (u >> 7) & 0xFF;
  int sane = ((e >= 97 && e <= 160) || (u & 0x7FFF) == 0) ? 1 : 0;
  atomicAdd(&cnt, sane);
  __syncthreads();
  if (threadIdx.x == 0) *flag = (cnt >= 56) ? 0 : 1;
}

// convert all small inputs (+freq) to fp32 in ws, per flag
__global__ __launch_bounds__(256) void cvt_kernel(CvtArgs a, float* ws, const int* flag) {
  int flg = *flag;
  int gt = blockIdx.x * 256 + threadIdx.x;
  int gs = gridDim.x * 256;
  for (int s = 0; s < 22; ++s) {
    const void* sp = a.src[s];
    int n = a.n[s];
    float* dst = ws + a.off[s];
    if (flg) {
      const float* f = (const float*)sp;
      for (int i = gt; i < n; i += gs) dst[i] = f[i];
    } else {
      const bf16* h = (const bf16*)sp;
      for (int i = gt; i < n; i += gs) dst[i] = b2f(h[i]);
    }
  }
}

// fallback: zero-fill (2 bytes/elem, safe under both out dtypes)
__global__ __launch_bounds__(256) void fill_zero_kernel(unsigned short* out, int n) {
  int i = blockIdx.x * 256 + threadIdx.x;
  if (i < n) out[i] = 0;
}

// ----------------------------------------------------------------------------
// setup: DCT matrices, E64 twiddles, wT = out_w^T (from converted fp32 outw)
// ----------------------------------------------------------------------------
__global__ __launch_bounds__(256) void setup_kernel(
    float* Dm, float* DT, float2* E64, float* wT, const float* out_w)
{
  int t = blockIdx.x * 256 + threadIdx.x;
  int NTH = gridDim.x * 256;
  const double PI = 3.14159265358979323846;
  for (int i = t; i < 64 * 64; i += NTH) {
    int n = i >> 6, x = i & 63;
    double v = cos((double)n * (((double)x + 0.5) / 64.0) * PI) * sqrt(2.0 / 64.0);
    if (n == 0) v *= 0.70710678118654752440;
    Dm[n * 64 + x] = (float)v;
    DT[x * 64 + n] = (float)v;
  }
  for (int i = t; i < 64 * 64; i += NTH) {
    int k = i >> 6, n = i & 63;
    int m = (k * n) & 63;
    double th = -2.0 * PI * (double)m / 64.0;
    E64[i] = make_float2((float)cos(th), (float)sin(th));
  }
  for (int i = t; i < 192 * 192; i += NTH) {
    int co = i / 192, c = i - co * 192;
    wT[c * 192 + co] = out_w[i];
  }
}

// ----------------------------------------------------------------------------
// depthwise 3x3 conv (NCHW in, NHWC fp32 out), pad 1. grid (6,64,32)
// ----------------------------------------------------------------------------
__global__ __launch_bounds__(256) void conv_kernel(
    const void* xin, const int* flag, const float* dww, const float* dwb, float* out)
{
  int flg = *flag;
  const float* xf = (const float*)xin;
  const bf16*  xb = (const bf16*)xin;
  int c0 = blockIdx.x * 32;
  int h  = blockIdx.y;
  int b  = blockIdx.z;
  __shared__ float in_s[3][32][66];
  __shared__ float wg[32][10];
  __shared__ float bias[32];
  int t = threadIdx.x;
  for (int idx = t; idx < 3 * 32 * 66; idx += 256) {
    int r = idx / (32 * 66);
    int rem = idx - r * (32 * 66);
    int ci = rem / 66, wi = rem - ci * 66;
    int hh = h + r - 1, wwi = wi - 1;
    float v = 0.f;
    if (hh >= 0 && hh < 64 && wwi >= 0 && wwi < 64) {
      size_t ix = (((size_t)b * 192 + c0 + ci) * 64 + hh) * 64 + wwi;
      v = flg ? xf[ix] : b2f(xb[ix]);
    }
    in_s[r][ci][wi] = v;
  }
  for (int idx = t; idx < 32 * 9; idx += 256) {
    int ci = idx / 9;
    wg[ci][idx - ci * 9] = dww[(c0 + ci) * 9 + (idx - ci * 9)];
  }
  if (t < 32) bias[t] = dwb[c0 + t];
  __syncthreads();
  int cc = t & 31, wq = t >> 5;
  for (int j = 0; j < 8; ++j) {
    int w = wq + 8 * j;
    float acc = bias[cc];
#pragma unroll
    for (int r = 0; r < 3; ++r)
#pragma unroll
      for (int kw = 0; kw < 3; ++kw)
        acc += in_s[r][cc][w + kw] * wg[cc][r * 3 + kw];
    out[(((size_t)b * 64 + h) * 64 + w) * 192 + c0 + cc] = acc;
  }
}

// ----------------------------------------------------------------------------
// linear: (131072 x 192) @ lin_w^T (384 x 192) + lin_b -> xh | z(bf16)
// grid (2048, 6)
// ----------------------------------------------------------------------------
__global__ __launch_bounds__(256) void linear_kernel(
    const float* A, const float* Wt, const float* bias, float* xh, bf16* zb)
{
  __shared__ float As[32][65];
  __shared__ float Bs[32][65];
  int m0 = blockIdx.x * 64, n0 = blockIdx.y * 64;
  int t = threadIdx.x, tx = t & 15, ty = t >> 4;
  float acc[4][4] = {};
  for (int k0 = 0; k0 < 192; k0 += 32) {
    int kk = t & 31, mm = t >> 5;
#pragma unroll
    for (int i = 0; i < 8; ++i) {
      As[kk][mm + 8 * i] = A[(size_t)(m0 + mm + 8 * i) * 192 + k0 + kk];
      Bs[kk][mm + 8 * i] = Wt[(size_t)(n0 + mm + 8 * i) * 192 + k0 + kk];
    }
    __syncthreads();
    for (int k = 0; k < 32; ++k) {
      float a[4], bb[4];
#pragma unroll
      for (int i = 0; i < 4; ++i) a[i] = As[k][ty * 4 + i];
#pragma unroll
      for (int j = 0; j < 4; ++j) bb[j] = Bs[k][tx * 4 + j];
#pragma unroll
      for (int i = 0; i < 4; ++i)
#pragma unroll
        for (int j = 0; j < 4; ++j) acc[i][j] += a[i] * bb[j];
    }
    __syncthreads();
  }
  for (int i = 0; i < 4; ++i) {
    int m = m0 + ty * 4 + i;
    for (int j = 0; j < 4; ++j) {
      int n = n0 + tx * 4 + j;
      float v = acc[i][j] + bias[n];
      if (n < 192) xh[(size_t)m * 192 + n] = v;
      else         zb[(size_t)m * 192 + (n - 192)] = __float2bfloat16(v);
    }
  }
}

// ----------------------------------------------------------------------------
// kmap: e = relu(freq @ tok_w^T + tok_b); k = exp(-((pi i/64)^2+(pi j/64)^2)*e)
// grid (64, 3)
// ----------------------------------------------------------------------------
__global__ __launch_bounds__(256) void kmap_kernel(
    const float* A, const float* Wt, const float* bias, float* kout)
{
  __shared__ float As[32][65];
  __shared__ float Bs[32][65];
  int m0 = blockIdx.x * 64, n0 = blockIdx.y * 64;
  int t = threadIdx.x, tx = t & 15, ty = t >> 4;
  float acc[4][4] = {};
  for (int k0 = 0; k0 < 192; k0 += 32) {
    int kk = t & 31, mm = t >> 5;
#pragma unroll
    for (int i = 0; i < 8; ++i) {
      As[kk][mm + 8 * i] = A[(size_t)(m0 + mm + 8 * i) * 192 + k0 + kk];
      Bs[kk][mm + 8 * i] = Wt[(size_t)(n0 + mm + 8 * i) * 192 + k0 + kk];
    }
    __syncthreads();
    for (int k = 0; k < 32; ++k) {
      float a[4], bb[4];
#pragma unroll
      for (int i = 0; i < 4; ++i) a[i] = As[k][ty * 4 + i];
#pragma unroll
      for (int j = 0; j < 4; ++j) bb[j] = Bs[k][tx * 4 + j];
#pragma unroll
      for (int i = 0; i < 4; ++i)
#pragma unroll
        for (int j = 0; j < 4; ++j) acc[i][j] += a[i] * bb[j];
    }
    __syncthreads();
  }
  const float PI2 = 9.86960440108935862f;
  for (int i = 0; i < 4; ++i) {
    int m = m0 + ty * 4 + i;
    int ii = m >> 6, jj = m & 63;
    float d2 = (PI2 / 4096.f) * (float)(ii * ii + jj * jj);
    for (int j = 0; j < 4; ++j) {
      int n = n0 + tx * 4 + j;
      float e = acc[i][j] + bias[n];
      e = e > 0.f ? e : 0.f;
      kout[(size_t)m * 192 + n] = expf(-d2 * e);
    }
  }
}

// ----------------------------------------------------------------------------
// pooled[b,c] = mean_{hw} xh ; grid (12, 32)
// ----------------------------------------------------------------------------
__global__ __launch_bounds__(256) void pool_kernel(const float* xh, float* pooled)
{
  int b = blockIdx.y;
  int ct = blockIdx.x * 16;
  int t = threadIdx.x;
  int cl = t & 15, rg = t >> 4;
  float s = 0.f;
  for (int p = rg; p < 4096; p += 16)
    s += scrub(xh[((size_t)b * 4096 + p) * 192 + ct + cl]);
  __shared__ float red[16][17];
  red[rg][cl] = s;
  __syncthreads();
  if (t < 16) {
    float tot = 0.f;
    for (int r = 0; r < 16; ++r) tot += red[r][t];
    pooled[b * 192 + ct + t] = tot * (1.f / 4096.f);
  }
}

// ----------------------------------------------------------------------------
// MLP + batchnorms + gumbel argmax -> sel[32] ; 1 block
// ----------------------------------------------------------------------------
__global__ __launch_bounds__(256) void mlp_kernel(
    const float* pooled, const float* gn,
    const float* p1w, const float* p1b, const float* g1, const float* b1,
    const float* p2w, const float* p2b, const float* g2, const float* b2,
    const float* p3w, const float* p3b, int* sel)
{
  __shared__ float pl[32 * 192];
  __shared__ float h1s[32 * 256];
  __shared__ float h2s[32 * 32];
  int t = threadIdx.x;
  for (int i = t; i < 32 * 192; i += 256) pl[i] = pooled[i];
  __syncthreads();
  {
    float acc[32];
    float bb = p1b[t];
#pragma unroll
    for (int b = 0; b < 32; ++b) acc[b] = bb;
    for (int c = 0; c < 192; ++c) {
      float w = p1w[t * 192 + c];
#pragma unroll
      for (int b = 0; b < 32; ++b) acc[b] += w * pl[b * 192 + c];
    }
    for (int b = 0; b < 32; ++b) {
      float v = acc[b];
      v = v > 0.f ? v : 0.1f * v;
      h1s[b * 256 + t] = v;
    }
  }
  __syncthreads();
  {
    float m = 0.f;
    for (int b = 0; b < 32; ++b) m += h1s[b * 256 + t];
    m *= (1.f / 32.f);
    float v = 0.f;
    for (int b = 0; b < 32; ++b) { float d = h1s[b * 256 + t] - m; v += d * d; }
    v *= (1.f / 32.f);
    float sc = g1[t] / sqrtf(v + 1e-5f);
    float sh = b1[t] - m * sc;
    for (int b = 0; b < 32; ++b) h1s[b * 256 + t] = h1s[b * 256 + t] * sc + sh;
  }
  __syncthreads();
  {
    int j = t & 31, bg = t >> 5;
    float acc[4];
    float bb = p2b[j];
    for (int i = 0; i < 4; ++i) acc[i] = bb;
    for (int c = 0; c < 256; ++c) {
      float w = p2w[j * 256 + c];
#pragma unroll
      for (int i = 0; i < 4; ++i) acc[i] += w * h1s[(bg * 4 + i) * 256 + c];
    }
    for (int i = 0; i < 4; ++i) {
      float v = acc[i];
      v = v > 0.f ? v : 0.1f * v;
      h2s[(bg * 4 + i) * 32 + j] = v;
    }
  }
  __syncthreads();
  if (t < 32) {
    float m = 0.f;
    for (int b = 0; b < 32; ++b) m += h2s[b * 32 + t];
    m *= (1.f / 32.f);
    float v = 0.f;
    for (int b = 0; b < 32; ++b) { float d = h2s[b * 32 + t] - m; v += d * d; }
    v *= (1.f / 32.f);
    float sc = g2[t] / sqrtf(v + 1e-5f);
    float sh = b2[t] - m * sc;
    for (int b = 0; b < 32; ++b) h2s[b * 32 + t] = h2s[b * 32 + t] * sc + sh;
  }
  __syncthreads();
  if (t < 32) {
    float best = -1e30f; int bi = 0;
    for (int r = 0; r < 3; ++r) {
      float l = p3b[r];
      for (int c = 0; c < 32; ++c) l += p3w[r * 32 + c] * h2s[t * 32 + c];
      l += gn[t * 3 + r];
      if (l > best) { best = l; bi = r; }
    }
    sel[t] = bi;
  }
}

// ----------------------------------------------------------------------------
// DCT stage over first axis of (64, 12288), in-place. grid (192, 32)
// ----------------------------------------------------------------------------
__global__ __launch_bounds__(256) void axis0_kernel(
    float* buf, const float* mat, const int* sel, int branch)
{
  int b = blockIdx.y;
  if (sel[b] != branch) return;
  int q0 = blockIdx.x * 64;
  __shared__ float mT[64][65];
  __shared__ float xs[64][65];
  int t = threadIdx.x;
  for (int i = t; i < 4096; i += 256) {
    int r = i >> 6, c = i & 63;
    mT[c][r] = mat[i];
    xs[r][c] = buf[(size_t)b * SLICE + r * 12288 + q0 + c];
  }
  __syncthreads();
  int tx = t & 15, ty = t >> 4;
  float acc[4][4] = {};
  for (int l = 0; l < 64; ++l) {
    float a[4], xv[4];
#pragma unroll
    for (int i = 0; i < 4; ++i) a[i] = mT[l][ty * 4 + i];
#pragma unroll
    for (int j = 0; j < 4; ++j) xv[j] = xs[l][tx * 4 + j];
#pragma unroll
    for (int i = 0; i < 4; ++i)
#pragma unroll
      for (int j = 0; j < 4; ++j) acc[i][j] += a[i] * xv[j];
  }
  float* ob = buf + (size_t)b * SLICE;
  for (int i = 0; i < 4; ++i)
    for (int j = 0; j < 4; ++j)
      ob[(ty * 4 + i) * 12288 + q0 + tx * 4 + j] = acc[i][j];
}

// DCT stage over middle axis, in-place, optional k multiply. grid (192, 32)
__global__ __launch_bounds__(256) void axis1_kernel(
    float* buf, const float* mat, const float* kmul, const int* sel, int branch)
{
  int b = blockIdx.y;
  if (sel[b] != branch) return;
  int n = blockIdx.x / 3;
  int ct = (blockIdx.x - n * 3) * 64;
  float* base = buf + (size_t)b * SLICE + n * (64 * 192) + ct;
  __shared__ float mT[64][65];
  __shared__ float xs[64][65];
  int t = threadIdx.x;
  for (int i = t; i < 4096; i += 256) {
    int r = i >> 6, c = i & 63;
    mT[c][r] = mat[i];
    xs[r][c] = base[r * 192 + c];
  }
  __syncthreads();
  int tx = t & 15, ty = t >> 4;
  float acc[4][4] = {};
  for (int l = 0; l < 64; ++l) {
    float a[4], xv[4];
#pragma unroll
    for (int i = 0; i < 4; ++i) a[i] = mT[l][ty * 4 + i];
#pragma unroll
    for (int j = 0; j < 4; ++j) xv[j] = xs[l][tx * 4 + j];
#pragma unroll
    for (int i = 0; i < 4; ++i)
#pragma unroll
      for (int j = 0; j < 4; ++j) acc[i][j] += a[i] * xv[j];
  }
  if (kmul) {
    for (int i = 0; i < 4; ++i)
      for (int j = 0; j < 4; ++j)
        acc[i][j] *= kmul[(size_t)(n * 64 + ty * 4 + i) * 192 + ct + tx * 4 + j];
  }
  for (int i = 0; i < 4; ++i)
    for (int j = 0; j < 4; ++j)
      base[(ty * 4 + i) * 192 + tx * 4 + j] = acc[i][j];
}

// ----------------------------------------------------------------------------
// FFT forward over h (real -> complex), real in-place into xh, imag -> Si
// ----------------------------------------------------------------------------
__global__ __launch_bounds__(256) void ffth_kernel(
    float* xh, float* Si, const float2* E64, const int* sel)
{
  int b = blockIdx.y;
  if (sel[b] != 1) return;
  int q0 = blockIdx.x * 64;
  __shared__ float er[64][65], ei[64][65], xs[64][65];
  int t = threadIdx.x;
  for (int i = t; i < 4096; i += 256) {
    int r = i >> 6, c = i & 63;
    float2 e = E64[i];
    er[r][c] = e.x; ei[r][c] = e.y;
    xs[r][c] = xh[(size_t)b * SLICE + r * 12288 + q0 + c];
  }
  __syncthreads();
  int tx = t & 15, ty = t >> 4;
  float ar[4][4] = {}, ai[4][4] = {};
  for (int l = 0; l < 64; ++l) {
    float e1[4], e2[4], xv[4];
#pragma unroll
    for (int i = 0; i < 4; ++i) { e1[i] = er[l][ty * 4 + i]; e2[i] = ei[l][ty * 4 + i]; }
#pragma unroll
    for (int j = 0; j < 4; ++j) xv[j] = xs[l][tx * 4 + j];
#pragma unroll
    for (int i = 0; i < 4; ++i)
#pragma unroll
      for (int j = 0; j < 4; ++j) { ar[i][j] += e1[i] * xv[j]; ai[i][j] += e2[i] * xv[j]; }
  }
  size_t ob = (size_t)b * SLICE;
  for (int i = 0; i < 4; ++i)
    for (int j = 0; j < 4; ++j) {
      size_t o = ob + (size_t)(ty * 4 + i) * 12288 + q0 + tx * 4 + j;
      xh[o] = ar[i][j];
      Si[o] = ai[i][j];
    }
}

// FFT over w (complex, in-place). grid (384, 32)
__global__ __launch_bounds__(256) void fftw_kernel(
    float* Sr, float* Si, const float2* E64, const int* sel, float s)
{
  int b = blockIdx.y;
  if (sel[b] != 1) return;
  int kh = blockIdx.x / 6;
  int ct = (blockIdx.x - kh * 6) * 32;
  float* br = Sr + (size_t)b * SLICE + kh * 12288 + ct;
  float* bi = Si + (size_t)b * SLICE + kh * 12288 + ct;
  __shared__ float er[64][65], ei[64][65];
  __shared__ float xr[64][33], xi[64][33];
  int t = threadIdx.x;
  for (int i = t; i < 4096; i += 256) {
    float2 e = E64[i];
    er[i >> 6][i & 63] = e.x;
    ei[i >> 6][i & 63] = s * e.y;
  }
  for (int i = t; i < 2048; i += 256) {
    int l = i >> 5, q = i & 31;
    xr[l][q] = br[l * 192 + q];
    xi[l][q] = bi[l * 192 + q];
  }
  __syncthreads();
  int tx = t & 7, ty = t >> 3;
  float ar[2][4] = {}, ac[2][4] = {};
  for (int l = 0; l < 64; ++l) {
    float e1a = er[l][ty],      e2a = ei[l][ty];
    float e1b = er[l][ty + 32], e2b = ei[l][ty + 32];
#pragma unroll
    for (int j = 0; j < 4; ++j) {
      float vr = xr[l][tx * 4 + j], vi = xi[l][tx * 4 + j];
      ar[0][j] += e1a * vr - e2a * vi;
      ac[0][j] += e1a * vi + e2a * vr;
      ar[1][j] += e1b * vr - e2b * vi;
      ac[1][j] += e1b * vi + e2b * vr;
    }
  }
  for (int r = 0; r < 2; ++r) {
    int kw = ty + r * 32;
    for (int j = 0; j < 4; ++j) {
      br[kw * 192 + tx * 4 + j] = ar[r][j];
      bi[kw * 192 + tx * 4 + j] = ac[r][j];
    }
  }
}

// ----------------------------------------------------------------------------
// Fused c-stage: S <- ((S @ E192) * k*SCALE) @ conj(E192), in-place per 32-row
// tile. Exact integer-phase twiddles from a 192-entry LDS table.
// grid (128, 32). LDS ~52 KB.
// ----------------------------------------------------------------------------
__global__ __launch_bounds__(256) void fftc_fused_kernel(
    float* Sr, float* Si, const float* kmap, const int* sel)
{
  int b = blockIdx.y;
  if (sel[b] != 1) return;
  int m0 = blockIdx.x * 32;
  float* br = Sr + (size_t)b * SLICE + (size_t)m0 * 192;
  float* bi = Si + (size_t)b * SLICE + (size_t)m0 * 192;
  __shared__ float Tr[192][33];
  __shared__ float Ti[192][33];
  __shared__ float cosT[192], sinT[192];
  int t = threadIdx.x;
  if (t < 192) {
    double th = -2.0 * 3.14159265358979323846 * (double)t / 192.0;
    cosT[t] = (float)cos(th);
    sinT[t] = (float)sin(th);
  }
  for (int i = t; i < 6144; i += 256) {
    int row = i / 192, c = i - row * 192;
    Tr[c][row] = br[i];
    Ti[c][row] = bi[i];
  }
  __syncthreads();
  int tx = t & 15, ty = t >> 4;
  int r0 = ty * 2, r1 = ty * 2 + 1;
  int f[12];
#pragma unroll
  for (int j = 0; j < 12; ++j) f[j] = tx * 12 + j;
  float ar[2][12] = {}, ai[2][12] = {};
  {
    int m[12];
#pragma unroll
    for (int j = 0; j < 12; ++j) m[j] = 0;
    for (int k = 0; k < 192; ++k) {
      float x0r = Tr[k][r0], x0i = Ti[k][r0];
      float x1r = Tr[k][r1], x1i = Ti[k][r1];
#pragma unroll
      for (int j = 0; j < 12; ++j) {
        float er = cosT[m[j]], ei = sinT[m[j]];
        ar[0][j] += x0r * er - x0i * ei;
        ai[0][j] += x0r * ei + x0i * er;
        ar[1][j] += x1r * er - x1i * ei;
        ai[1][j] += x1r * ei + x1i * er;
        m[j] += f[j]; if (m[j] >= 192) m[j] -= 192;
      }
    }
  }
  const float SCALE = 1.0f / 786432.0f;
#pragma unroll
  for (int r = 0; r < 2; ++r)
#pragma unroll
    for (int j = 0; j < 12; ++j) {
      float kv = kmap[(size_t)(m0 + ty * 2 + r) * 192 + tx * 12 + j] * SCALE;
      ar[r][j] *= kv; ai[r][j] *= kv;
    }
  __syncthreads();
  for (int r = 0; r < 2; ++r)
    for (int j = 0; j < 12; ++j) {
      Tr[tx * 12 + j][ty * 2 + r] = ar[r][j];
      Ti[tx * 12 + j][ty * 2 + r] = ai[r][j];
    }
  __syncthreads();
  float or_[2][12] = {}, oi[2][12] = {};
  {
    int m[12];
#pragma unroll
    for (int j = 0; j < 12; ++j) m[j] = 0;
    for (int k = 0; k < 192; ++k) {
      float x0r = Tr[k][r0], x0i = Ti[k][r0];
      float x1r = Tr[k][r1], x1i = Ti[k][r1];
#pragma unroll
      for (int j = 0; j < 12; ++j) {
        // multiply by conj(w) = cosT - i*sinT
        float er = cosT[m[j]], ei = sinT[m[j]];
        or_[0][j] += x0r * er + x0i * ei;
        oi[0][j]  += x0i * er - x0r * ei;
        or_[1][j] += x1r * er + x1i * ei;
        oi[1][j]  += x1i * er - x1r * ei;
        m[j] += f[j]; if (m[j] >= 192) m[j] -= 192;
      }
    }
  }
  for (int r = 0; r < 2; ++r)
    for (int j = 0; j < 12; ++j) {
      br[(ty * 2 + r) * 192 + tx * 12 + j] = or_[r][j];
      bi[(ty * 2 + r) * 192 + tx * 12 + j] = oi[r][j];
    }
}

// inverse h-stage, real part only, in-place into xh. grid (384, 32)
__global__ __launch_bounds__(256) void ffthi_kernel(
    float* Sr, const float* Si, const float2* E64, const int* sel)
{
  int b = blockIdx.y;
  if (sel[b] != 1) return;
  int q0 = blockIdx.x * 32;
  __shared__ float er[64][65], ei[64][65];
  __shared__ float xr[64][33], xi[64][33];
  int t = threadIdx.x;
  for (int i = t; i < 4096; i += 256) {
    float2 e = E64[i];
    er[i >> 6][i & 63] = e.x;
    ei[i >> 6][i & 63] = e.y;
  }
  for (int i = t; i < 2048; i += 256) {
    int l = i >> 5, q = i & 31;
    size_t o = (size_t)b * SLICE + (size_t)l * 12288 + q0 + q;
    xr[l][q] = Sr[o];
    xi[l][q] = Si[o];
  }
  __syncthreads();
  int tx = t & 7, ty = t >> 3;
  float acc[2][4] = {};
  for (int l = 0; l < 64; ++l) {
    float e1a = er[l][ty],      e2a = ei[l][ty];
    float e1b = er[l][ty + 32], e2b = ei[l][ty + 32];
#pragma unroll
    for (int j = 0; j < 4; ++j) {
      float vr = xr[l][tx * 4 + j], vi = xi[l][tx * 4 + j];
      acc[0][j] += e1a * vr + e2a * vi;   // Re(e^{+i th} A), ei = -sin
      acc[1][j] += e1b * vr + e2b * vi;
    }
  }
  for (int r = 0; r < 2; ++r) {
    int h = ty + r * 32;
    for (int j = 0; j < 4; ++j)
      Sr[(size_t)b * SLICE + (size_t)h * 12288 + q0 + tx * 4 + j] = acc[r][j];
  }
}

// ----------------------------------------------------------------------------
// Haar branch, in-place on xh (haar along C: 64-chunks then full 192)
// grid (128, 32)
// ----------------------------------------------------------------------------
__global__ __launch_bounds__(256) void haar_kernel(
    float* xh, const float* kmap, const int* sel)
{
  int b = blockIdx.y;
  if (sel[b] != 2) return;
  int h = blockIdx.x >> 1;
  int w0 = (blockIdx.x & 1) * 32;
  size_t base = (size_t)b * SLICE + ((size_t)h * 64 + w0) * 192;
  __shared__ float A[32 * 192];
  __shared__ float Bf[32 * 192];
  int t = threadIdx.x;
  for (int i = t; i < 6144; i += 256) A[i] = xh[base + i];
  __syncthreads();
  for (int u = t; u < 32 * 96; u += 256) {
    int p = u / 96, r = u - p * 96;
    int ch = r >> 5, i = r & 31;
    float v0 = A[p * 192 + ch * 64 + 2 * i];
    float v1 = A[p * 192 + ch * 64 + 2 * i + 1];
    Bf[p * 192 + ch * 64 + i]      = (v0 + v1) * 0.5f;
    Bf[p * 192 + ch * 64 + 32 + i] = (v0 - v1) * 0.5f;
  }
  __syncthreads();
  for (int u = t; u < 32 * 96; u += 256) {
    int p = u / 96, i = u - p * 96;
    float v0 = Bf[p * 192 + 2 * i];
    float v1 = Bf[p * 192 + 2 * i + 1];
    A[p * 192 + i]      = (v0 + v1) * 0.5f;
    A[p * 192 + 96 + i] = (v0 - v1) * 0.5f;
  }
  __syncthreads();
  for (int i = t; i < 6144; i += 256)
    A[i] *= kmap[((size_t)h * 64 + w0) * 192 + i];
  __syncthreads();
  for (int u = t; u < 32 * 96; u += 256) {
    int p = u / 96, r = u - p * 96;
    int ch = r >> 5, i = r & 31;
    float a = A[p * 192 + ch * 64 + i];
    float d = A[p * 192 + ch * 64 + 32 + i];
    Bf[p * 192 + ch * 64 + 2 * i]     = a + d;
    Bf[p * 192 + ch * 64 + 2 * i + 1] = a - d;
  }
  __syncthreads();
  for (int u = t; u < 32 * 96; u += 256) {
    int p = u / 96, i = u - p * 96;
    float a = Bf[p * 192 + i];
    float d = Bf[p * 192 + 96 + i];
    A[p * 192 + 2 * i]     = a + d;
    A[p * 192 + 2 * i + 1] = a - d;
  }
  __syncthreads();
  for (int i = t; i < 6144; i += 256) xh[base + i] = A[i];
}

// ----------------------------------------------------------------------------
// final: LN(c) * silu(z) @ out_w^T + out_b, dual-dtype store. grid 2048
// ----------------------------------------------------------------------------
__global__ __launch_bounds__(256) void final_kernel(
    const float* comb, const bf16* zb, const float* lng, const float* lnb,
    const float* wT, const float* outb, void* outp, const int* flag)
{
  int flg = *flag;
  int bi = blockIdx.x;
  int b = bi >> 6, h = bi & 63;
  size_t base = ((size_t)b * 4096 + (size_t)h * 64) * 192;
  __shared__ float As[64 * 194];
  __shared__ float mu[64], rs[64];
  int t = threadIdx.x;
  for (int e = t; e < 12288; e += 256) {
    int p = e / 192, c = e - p * 192;
    As[p * 194 + c] = scrub(comb[base + e]);
  }
  __syncthreads();
  if (t < 64) {
    float s = 0.f;
    for (int c = 0; c < 192; ++c) s += As[t * 194 + c];
    float m = s * (1.f / 192.f);
    float v = 0.f;
    for (int c = 0; c < 192; ++c) { float d = As[t * 194 + c] - m; v += d * d; }
    v *= (1.f / 192.f);
    mu[t] = m;
    rs[t] = 1.f / sqrtf(v + 1e-5f);
  }
  __syncthreads();
  for (int e = t; e < 12288; e += 256) {
    int p = e / 192, c = e - p * 192;
    float v = (As[p * 194 + c] - mu[p]) * rs[p] * lng[c] + lnb[c];
    float zv = scrub(b2f(zb[base + e]));
    v *= zv / (1.f + expf(-zv));
    As[p * 194 + c] = v;
  }
  __syncthreads();
  int tx = t & 15, ty = t >> 4;
  float acc[4][12];
  for (int i = 0; i < 4; ++i)
    for (int j = 0; j < 12; ++j) acc[i][j] = 0.f;
  for (int c = 0; c < 192; ++c) {
    float av[4];
#pragma unroll
    for (int i = 0; i < 4; ++i) av[i] = As[(ty * 4 + i) * 194 + c];
    float wv[12];
#pragma unroll
    for (int j = 0; j < 12; ++j) wv[j] = wT[(size_t)c * 192 + tx * 12 + j];
#pragma unroll
    for (int i = 0; i < 4; ++i)
#pragma unroll
      for (int j = 0; j < 12; ++j) acc[i][j] += av[i] * wv[j];
  }
  __syncthreads();
  for (int i = 0; i < 4; ++i)
    for (int j = 0; j < 12; ++j) {
      int co = tx * 12 + j, p = ty * 4 + i;
      As[co * 64 + p] = acc[i][j] + outb[co];
    }
  __syncthreads();
  for (int e = t; e < 12288; e += 256) {
    int co = e >> 6, w = e & 63;
    size_t oi = (((size_t)b * 192 + co) * 64 + h) * 64 + w;
    if (flg) ((float*)outp)[oi] = As[e];
    else     ((bf16*)outp)[oi] = __float2bfloat16(As[e]);
  }
}

// ----------------------------------------------------------------------------
extern "C" void kernel_launch(void* const* d_in, const int* in_sizes, int n_in,
                              void* d_out, int out_size, void* d_ws, size_t ws_size,
                              hipStream_t stream) {
  (void)in_sizes; (void)n_in;
  if (ws_size < WS_NEEDED_BYTES) {
    fill_zero_kernel<<<(out_size + 255) / 256, 256, 0, stream>>>(
        (unsigned short*)d_out, out_size);
    return;
  }
  float* ws    = (float*)d_ws;
  float* xh    = ws + O_XH;
  float* Si    = ws + O_SI;
  bf16*  zb    = (bf16*)(ws + O_ZB);
  float* kmap  = ws + O_KMAP;
  float2* E64  = (float2*)(ws + O_E64);
  float* Dm    = ws + O_DM;
  float* DT    = ws + O_DT;
  float* wT    = ws + O_WT;
  float* pooled= ws + O_POOL;
  int*   sel   = (int*)(ws + O_SEL);
  int*   flag  = (int*)(ws + O_FLAG);

  sniff_kernel<<<1, 64, 0, stream>>>((const unsigned short*)d_in[0], flag);

  CvtArgs ca;
  const int srcidx[22] = {2,3,4,5,6,7,8,9,10,11,12,13,14,15,16,17,18,19,20,21,22,1};
  const int ns[22] = {96,1728,192,73728,384,49152,256,256,256,8192,32,32,32,96,3,
                      36864,192,192,192,36864,192,786432};
  const long long offs[22] = {
    (long long)W_GN,(long long)W_DWW,(long long)W_DWB,(long long)W_LINW,
    (long long)W_LINB,(long long)W_P1W,(long long)W_P1B,(long long)W_G1,
    (long long)W_B1,(long long)W_P2W,(long long)W_P2B,(long long)W_G2,
    (long long)W_B2,(long long)W_P3W,(long long)W_P3B,(long long)W_TOKW,
    (long long)W_TOKB,(long long)W_LNG,(long long)W_LNB,(long long)W_OUTW,
    (long long)W_OUTB,(long long)O_FREQ};
  for (int i = 0; i < 22; ++i) { ca.src[i] = d_in[srcidx[i]]; ca.n[i] = ns[i]; ca.off[i] = offs[i]; }
  cvt_kernel<<<64, 256, 0, stream>>>(ca, ws, flag);

  setup_kernel<<<64, 256, 0, stream>>>(Dm, DT, E64, wT, ws + W_OUTW);
  conv_kernel<<<dim3(6, 64, 32), 256, 0, stream>>>(d_in[0], flag, ws + W_DWW, ws + W_DWB, Si);
  linear_kernel<<<dim3(2048, 6), 256, 0, stream>>>(Si, ws + W_LINW, ws + W_LINB, xh, zb);
  pool_kernel<<<dim3(12, 32), 256, 0, stream>>>(xh, pooled);
  mlp_kernel<<<1, 256, 0, stream>>>(pooled, ws + W_GN,
      ws + W_P1W, ws + W_P1B, ws + W_G1, ws + W_B1,
      ws + W_P2W, ws + W_P2B, ws + W_G2, ws + W_B2,
      ws + W_P3W, ws + W_P3B, sel);
  kmap_kernel<<<dim3(64, 3), 256, 0, stream>>>(ws + O_FREQ, ws + W_TOKW, ws + W_TOKB, kmap);
  // DCT branch (sel==0), in-place on xh
  axis0_kernel<<<dim3(192, 32), 256, 0, stream>>>(xh, Dm, sel, 0);
  axis1_kernel<<<dim3(192, 32), 256, 0, stream>>>(xh, Dm, kmap, sel, 0);
  axis1_kernel<<<dim3(192, 32), 256, 0, stream>>>(xh, DT, nullptr, sel, 0);
  axis0_kernel<<<dim3(192, 32), 256, 0, stream>>>(xh, DT, sel, 0);
  // FFT branch (sel==1); b-axis FFT/IFFT cancels analytically; in-place (xh,Si)
  ffth_kernel<<<dim3(192, 32), 256, 0, stream>>>(xh, Si, E64, sel);
  fftw_kernel<<<dim3(384, 32), 256, 0, stream>>>(xh, Si, E64, sel, 1.f);
  fftc_fused_kernel<<<dim3(128, 32), 256, 0, stream>>>(xh, Si, kmap, sel);
  fftw_kernel<<<dim3(384, 32), 256, 0, stream>>>(xh, Si, E64, sel, -1.f);
  ffthi_kernel<<<dim3(384, 32), 256, 0, stream>>>(xh, Si, E64, sel);
  // Haar branch (sel==2), in-place on xh
  haar_kernel<<<dim3(128, 32), 256, 0, stream>>>(xh, kmap, sel);
  // epilogue
  final_kernel<<<2048, 256, 0, stream>>>(xh, zb, ws + W_LNG, ws + W_LNB,
                                         wT, ws + W_OUTB, d_out, flag);
}

// Round 4
// 1994.643 us; speedup vs baseline: 1.0781x; 1.0781x over previous
//
#include <hip/hip_runtime.h>
#include <hip/hip_bf16.h>
#include <math.h>

typedef __hip_bfloat16 bf16;
#define DEVI __device__ __forceinline__
static DEVI float b2f(bf16 v) { return __bfloat162float(v); }
static DEVI float scrub(float v) { return (v - v == 0.f) ? v : 0.f; }

constexpr int SLICE = 64 * 64 * 192;           // per-b elements = 786432

// ws layout (float offsets). Total 64,755,812 floats = 259,023,248 B (~247 MiB)
constexpr size_t O_XH   = 0;          // 25165824
constexpr size_t O_SI   = 25165824;   // 25165824
constexpr size_t O_ZB   = 50331648;   // bf16 z (25165824 elems = 12582912 slots)
constexpr size_t O_KMAP = 62914560;   // 786432
constexpr size_t O_FREQ = 63700992;   // 786432 (converted fp32 freq_embed)
constexpr size_t O_E64  = 64487424;   // 8192 (4096 float2)
constexpr size_t O_DM   = 64495616;   // 4096
constexpr size_t O_DT   = 64499712;   // 4096
constexpr size_t O_WT   = 64503808;   // 36864
constexpr size_t O_POOL = 64540672;   // 6144
constexpr size_t O_SEL  = 64546816;   // 32
constexpr size_t O_FLAG = 64546848;   // 32 (flag int + pad)
constexpr size_t O_W    = 64546880;   // 208932 packed fp32 weights
constexpr size_t WS_NEEDED_BYTES = (size_t)64755812 * 4;

// packed-weight offsets (relative to ws base)
constexpr size_t W_GN   = O_W + 0;      // 96
constexpr size_t W_DWW  = O_W + 96;     // 1728
constexpr size_t W_DWB  = O_W + 1824;   // 192
constexpr size_t W_LINW = O_W + 2016;   // 73728
constexpr size_t W_LINB = O_W + 75744;  // 384
constexpr size_t W_P1W  = O_W + 76128;  // 49152
constexpr size_t W_P1B  = O_W + 125280; // 256
constexpr size_t W_G1   = O_W + 125536; // 256
constexpr size_t W_B1   = O_W + 125792; // 256
constexpr size_t W_P2W  = O_W + 126048; // 8192
constexpr size_t W_P2B  = O_W + 134240; // 32
constexpr size_t W_G2   = O_W + 134272; // 32
constexpr size_t W_B2   = O_W + 134304; // 32
constexpr size_t W_P3W  = O_W + 134336; // 96
constexpr size_t W_P3B  = O_W + 134432; // 4 (3 used)
constexpr size_t W_TOKW = O_W + 134436; // 36864
constexpr size_t W_TOKB = O_W + 171300; // 192
constexpr size_t W_LNG  = O_W + 171492; // 192
constexpr size_t W_LNB  = O_W + 171684; // 192
constexpr size_t W_OUTW = O_W + 171876; // 36864
constexpr size_t W_OUTB = O_W + 208740; // 192

struct CvtArgs {
  const void* src[22];
  int n[22];
  long long off[22];   // float offset into ws
};

// ----------------------------------------------------------------------------
// dtype sniff: bf16 array -> ~64/64 sane uint16 exponents; fp32 -> ~40/64
// flag: 0 = bf16 inputs, 1 = fp32 inputs
// ----------------------------------------------------------------------------
__global__ void sniff_kernel(const unsigned short* xu, int* flag) {
  __shared__ int cnt;
  if (threadIdx.x == 0) cnt = 0;
  __syncthreads();
  unsigned short u = xu[threadIdx.x];
  int e = (u >> 7) & 0xFF;
  int sane = ((e >= 97 && e <= 160) || (u & 0x7FFF) == 0) ? 1 : 0;
  atomicAdd(&cnt, sane);
  __syncthreads();
  if (threadIdx.x == 0) *flag = (cnt >= 56) ? 0 : 1;
}

// convert all small inputs (+freq) to fp32 in ws, per flag
__global__ __launch_bounds__(256) void cvt_kernel(CvtArgs a, float* ws, const int* flag) {
  int flg = *flag;
  int gt = blockIdx.x * 256 + threadIdx.x;
  int gs = gridDim.x * 256;
  for (int s = 0; s < 22; ++s) {
    const void* sp = a.src[s];
    int n = a.n[s];
    float* dst = ws + a.off[s];
    if (flg) {
      const float* f = (const float*)sp;
      for (int i = gt; i < n; i += gs) dst[i] = f[i];
    } else {
      const bf16* h = (const bf16*)sp;
      for (int i = gt; i < n; i += gs) dst[i] = b2f(h[i]);
    }
  }
}

// fallback: zero-fill (2 bytes/elem, safe under both out dtypes)
__global__ __launch_bounds__(256) void fill_zero_kernel(unsigned short* out, int n) {
  int i = blockIdx.x * 256 + threadIdx.x;
  if (i < n) out[i] = 0;
}

// ----------------------------------------------------------------------------
// setup: DCT matrices, E64 twiddles, wT = out_w^T (from converted fp32 outw)
// ----------------------------------------------------------------------------
__global__ __launch_bounds__(256) void setup_kernel(
    float* Dm, float* DT, float2* E64, float* wT, const float* out_w)
{
  int t = blockIdx.x * 256 + threadIdx.x;
  int NTH = gridDim.x * 256;
  const double PI = 3.14159265358979323846;
  for (int i = t; i < 64 * 64; i += NTH) {
    int n = i >> 6, x = i & 63;
    double v = cos((double)n * (((double)x + 0.5) / 64.0) * PI) * sqrt(2.0 / 64.0);
    if (n == 0) v *= 0.70710678118654752440;
    Dm[n * 64 + x] = (float)v;
    DT[x * 64 + n] = (float)v;
  }
  for (int i = t; i < 64 * 64; i += NTH) {
    int k = i >> 6, n = i & 63;
    int m = (k * n) & 63;
    double th = -2.0 * PI * (double)m / 64.0;
    E64[i] = make_float2((float)cos(th), (float)sin(th));
  }
  for (int i = t; i < 192 * 192; i += NTH) {
    int co = i / 192, c = i - co * 192;
    wT[c * 192 + co] = out_w[i];
  }
}

// ----------------------------------------------------------------------------
// depthwise 3x3 conv (NCHW in, NHWC fp32 out), pad 1. grid (6,64,32)
// ----------------------------------------------------------------------------
__global__ __launch_bounds__(256) void conv_kernel(
    const void* xin, const int* flag, const float* dww, const float* dwb, float* out)
{
  int flg = *flag;
  const float* xf = (const float*)xin;
  const bf16*  xb = (const bf16*)xin;
  int c0 = blockIdx.x * 32;
  int h  = blockIdx.y;
  int b  = blockIdx.z;
  __shared__ float in_s[3][32][66];
  __shared__ float wg[32][10];
  __shared__ float bias[32];
  int t = threadIdx.x;
  for (int idx = t; idx < 3 * 32 * 66; idx += 256) {
    int r = idx / (32 * 66);
    int rem = idx - r * (32 * 66);
    int ci = rem / 66, wi = rem - ci * 66;
    int hh = h + r - 1, wwi = wi - 1;
    float v = 0.f;
    if (hh >= 0 && hh < 64 && wwi >= 0 && wwi < 64) {
      size_t ix = (((size_t)b * 192 + c0 + ci) * 64 + hh) * 64 + wwi;
      v = flg ? xf[ix] : b2f(xb[ix]);
    }
    in_s[r][ci][wi] = v;
  }
  for (int idx = t; idx < 32 * 9; idx += 256) {
    int ci = idx / 9;
    wg[ci][idx - ci * 9] = dww[(c0 + ci) * 9 + (idx - ci * 9)];
  }
  if (t < 32) bias[t] = dwb[c0 + t];
  __syncthreads();
  int cc = t & 31, wq = t >> 5;
  for (int j = 0; j < 8; ++j) {
    int w = wq + 8 * j;
    float acc = bias[cc];
#pragma unroll
    for (int r = 0; r < 3; ++r)
#pragma unroll
      for (int kw = 0; kw < 3; ++kw)
        acc += in_s[r][cc][w + kw] * wg[cc][r * 3 + kw];
    out[(((size_t)b * 64 + h) * 64 + w) * 192 + c0 + cc] = acc;
  }
}

// ----------------------------------------------------------------------------
// linear: (131072 x 192) @ lin_w^T (384 x 192) + lin_b -> xh | z(bf16)
// grid (2048, 6)
// ----------------------------------------------------------------------------
__global__ __launch_bounds__(256) void linear_kernel(
    const float* A, const float* Wt, const float* bias, float* xh, bf16* zb)
{
  __shared__ float As[32][65];
  __shared__ float Bs[32][65];
  int m0 = blockIdx.x * 64, n0 = blockIdx.y * 64;
  int t = threadIdx.x, tx = t & 15, ty = t >> 4;
  float acc[4][4] = {};
  for (int k0 = 0; k0 < 192; k0 += 32) {
    int kk = t & 31, mm = t >> 5;
#pragma unroll
    for (int i = 0; i < 8; ++i) {
      As[kk][mm + 8 * i] = A[(size_t)(m0 + mm + 8 * i) * 192 + k0 + kk];
      Bs[kk][mm + 8 * i] = Wt[(size_t)(n0 + mm + 8 * i) * 192 + k0 + kk];
    }
    __syncthreads();
    for (int k = 0; k < 32; ++k) {
      float a[4], bb[4];
#pragma unroll
      for (int i = 0; i < 4; ++i) a[i] = As[k][ty * 4 + i];
#pragma unroll
      for (int j = 0; j < 4; ++j) bb[j] = Bs[k][tx * 4 + j];
#pragma unroll
      for (int i = 0; i < 4; ++i)
#pragma unroll
        for (int j = 0; j < 4; ++j) acc[i][j] += a[i] * bb[j];
    }
    __syncthreads();
  }
  for (int i = 0; i < 4; ++i) {
    int m = m0 + ty * 4 + i;
    for (int j = 0; j < 4; ++j) {
      int n = n0 + tx * 4 + j;
      float v = acc[i][j] + bias[n];
      if (n < 192) xh[(size_t)m * 192 + n] = v;
      else         zb[(size_t)m * 192 + (n - 192)] = __float2bfloat16(v);
    }
  }
}

// ----------------------------------------------------------------------------
// kmap: e = relu(freq @ tok_w^T + tok_b); k = exp(-((pi i/64)^2+(pi j/64)^2)*e)
// grid (64, 3)
// ----------------------------------------------------------------------------
__global__ __launch_bounds__(256) void kmap_kernel(
    const float* A, const float* Wt, const float* bias, float* kout)
{
  __shared__ float As[32][65];
  __shared__ float Bs[32][65];
  int m0 = blockIdx.x * 64, n0 = blockIdx.y * 64;
  int t = threadIdx.x, tx = t & 15, ty = t >> 4;
  float acc[4][4] = {};
  for (int k0 = 0; k0 < 192; k0 += 32) {
    int kk = t & 31, mm = t >> 5;
#pragma unroll
    for (int i = 0; i < 8; ++i) {
      As[kk][mm + 8 * i] = A[(size_t)(m0 + mm + 8 * i) * 192 + k0 + kk];
      Bs[kk][mm + 8 * i] = Wt[(size_t)(n0 + mm + 8 * i) * 192 + k0 + kk];
    }
    __syncthreads();
    for (int k = 0; k < 32; ++k) {
      float a[4], bb[4];
#pragma unroll
      for (int i = 0; i < 4; ++i) a[i] = As[k][ty * 4 + i];
#pragma unroll
      for (int j = 0; j < 4; ++j) bb[j] = Bs[k][tx * 4 + j];
#pragma unroll
      for (int i = 0; i < 4; ++i)
#pragma unroll
        for (int j = 0; j < 4; ++j) acc[i][j] += a[i] * bb[j];
    }
    __syncthreads();
  }
  const float PI2 = 9.86960440108935862f;
  for (int i = 0; i < 4; ++i) {
    int m = m0 + ty * 4 + i;
    int ii = m >> 6, jj = m & 63;
    float d2 = (PI2 / 4096.f) * (float)(ii * ii + jj * jj);
    for (int j = 0; j < 4; ++j) {
      int n = n0 + tx * 4 + j;
      float e = acc[i][j] + bias[n];
      e = e > 0.f ? e : 0.f;
      kout[(size_t)m * 192 + n] = expf(-d2 * e);
    }
  }
}

// ----------------------------------------------------------------------------
// pooled[b,c] = mean_{hw} xh ; grid (12, 32)
// ----------------------------------------------------------------------------
__global__ __launch_bounds__(256) void pool_kernel(const float* xh, float* pooled)
{
  int b = blockIdx.y;
  int ct = blockIdx.x * 16;
  int t = threadIdx.x;
  int cl = t & 15, rg = t >> 4;
  float s = 0.f;
  for (int p = rg; p < 4096; p += 16)
    s += scrub(xh[((size_t)b * 4096 + p) * 192 + ct + cl]);
  __shared__ float red[16][17];
  red[rg][cl] = s;
  __syncthreads();
  if (t < 16) {
    float tot = 0.f;
    for (int r = 0; r < 16; ++r) tot += red[r][t];
    pooled[b * 192 + ct + t] = tot * (1.f / 4096.f);
  }
}

// ----------------------------------------------------------------------------
// MLP + batchnorms + gumbel argmax -> sel[32] ; 1 block
// ----------------------------------------------------------------------------
__global__ __launch_bounds__(256) void mlp_kernel(
    const float* pooled, const float* gn,
    const float* p1w, const float* p1b, const float* g1, const float* b1,
    const float* p2w, const float* p2b, const float* g2, const float* b2,
    const float* p3w, const float* p3b, int* sel)
{
  __shared__ float pl[32 * 192];
  __shared__ float h1s[32 * 256];
  __shared__ float h2s[32 * 32];
  int t = threadIdx.x;
  for (int i = t; i < 32 * 192; i += 256) pl[i] = pooled[i];
  __syncthreads();
  {
    float acc[32];
    float bb = p1b[t];
#pragma unroll
    for (int b = 0; b < 32; ++b) acc[b] = bb;
    for (int c = 0; c < 192; ++c) {
      float w = p1w[t * 192 + c];
#pragma unroll
      for (int b = 0; b < 32; ++b) acc[b] += w * pl[b * 192 + c];
    }
    for (int b = 0; b < 32; ++b) {
      float v = acc[b];
      v = v > 0.f ? v : 0.1f * v;
      h1s[b * 256 + t] = v;
    }
  }
  __syncthreads();
  {
    float m = 0.f;
    for (int b = 0; b < 32; ++b) m += h1s[b * 256 + t];
    m *= (1.f / 32.f);
    float v = 0.f;
    for (int b = 0; b < 32; ++b) { float d = h1s[b * 256 + t] - m; v += d * d; }
    v *= (1.f / 32.f);
    float sc = g1[t] / sqrtf(v + 1e-5f);
    float sh = b1[t] - m * sc;
    for (int b = 0; b < 32; ++b) h1s[b * 256 + t] = h1s[b * 256 + t] * sc + sh;
  }
  __syncthreads();
  {
    int j = t & 31, bg = t >> 5;
    float acc[4];
    float bb = p2b[j];
    for (int i = 0; i < 4; ++i) acc[i] = bb;
    for (int c = 0; c < 256; ++c) {
      float w = p2w[j * 256 + c];
#pragma unroll
      for (int i = 0; i < 4; ++i) acc[i] += w * h1s[(bg * 4 + i) * 256 + c];
    }
    for (int i = 0; i < 4; ++i) {
      float v = acc[i];
      v = v > 0.f ? v : 0.1f * v;
      h2s[(bg * 4 + i) * 32 + j] = v;
    }
  }
  __syncthreads();
  if (t < 32) {
    float m = 0.f;
    for (int b = 0; b < 32; ++b) m += h2s[b * 32 + t];
    m *= (1.f / 32.f);
    float v = 0.f;
    for (int b = 0; b < 32; ++b) { float d = h2s[b * 32 + t] - m; v += d * d; }
    v *= (1.f / 32.f);
    float sc = g2[t] / sqrtf(v + 1e-5f);
    float sh = b2[t] - m * sc;
    for (int b = 0; b < 32; ++b) h2s[b * 32 + t] = h2s[b * 32 + t] * sc + sh;
  }
  __syncthreads();
  if (t < 32) {
    float best = -1e30f; int bi = 0;
    for (int r = 0; r < 3; ++r) {
      float l = p3b[r];
      for (int c = 0; c < 32; ++c) l += p3w[r * 32 + c] * h2s[t * 32 + c];
      l += gn[t * 3 + r];
      if (l > best) { best = l; bi = r; }
    }
    sel[t] = bi;
  }
}

// ----------------------------------------------------------------------------
// DCT stage over first axis of (64, 12288), in-place. grid (192, 32)
// ----------------------------------------------------------------------------
__global__ __launch_bounds__(256) void axis0_kernel(
    float* buf, const float* mat, const int* sel, int branch)
{
  int b = blockIdx.y;
  if (sel[b] != branch) return;
  int q0 = blockIdx.x * 64;
  __shared__ float mT[64][65];
  __shared__ float xs[64][65];
  int t = threadIdx.x;
  for (int i = t; i < 4096; i += 256) {
    int r = i >> 6, c = i & 63;
    mT[c][r] = mat[i];
    xs[r][c] = buf[(size_t)b * SLICE + r * 12288 + q0 + c];
  }
  __syncthreads();
  int tx = t & 15, ty = t >> 4;
  float acc[4][4] = {};
  for (int l = 0; l < 64; ++l) {
    float a[4], xv[4];
#pragma unroll
    for (int i = 0; i < 4; ++i) a[i] = mT[l][ty * 4 + i];
#pragma unroll
    for (int j = 0; j < 4; ++j) xv[j] = xs[l][tx * 4 + j];
#pragma unroll
    for (int i = 0; i < 4; ++i)
#pragma unroll
      for (int j = 0; j < 4; ++j) acc[i][j] += a[i] * xv[j];
  }
  float* ob = buf + (size_t)b * SLICE;
  for (int i = 0; i < 4; ++i)
    for (int j = 0; j < 4; ++j)
      ob[(ty * 4 + i) * 12288 + q0 + tx * 4 + j] = acc[i][j];
}

// DCT stage over middle axis, in-place, optional k multiply. grid (192, 32)
__global__ __launch_bounds__(256) void axis1_kernel(
    float* buf, const float* mat, const float* kmul, const int* sel, int branch)
{
  int b = blockIdx.y;
  if (sel[b] != branch) return;
  int n = blockIdx.x / 3;
  int ct = (blockIdx.x - n * 3) * 64;
  float* base = buf + (size_t)b * SLICE + n * (64 * 192) + ct;
  __shared__ float mT[64][65];
  __shared__ float xs[64][65];
  int t = threadIdx.x;
  for (int i = t; i < 4096; i += 256) {
    int r = i >> 6, c = i & 63;
    mT[c][r] = mat[i];
    xs[r][c] = base[r * 192 + c];
  }
  __syncthreads();
  int tx = t & 15, ty = t >> 4;
  float acc[4][4] = {};
  for (int l = 0; l < 64; ++l) {
    float a[4], xv[4];
#pragma unroll
    for (int i = 0; i < 4; ++i) a[i] = mT[l][ty * 4 + i];
#pragma unroll
    for (int j = 0; j < 4; ++j) xv[j] = xs[l][tx * 4 + j];
#pragma unroll
    for (int i = 0; i < 4; ++i)
#pragma unroll
      for (int j = 0; j < 4; ++j) acc[i][j] += a[i] * xv[j];
  }
  if (kmul) {
    for (int i = 0; i < 4; ++i)
      for (int j = 0; j < 4; ++j)
        acc[i][j] *= kmul[(size_t)(n * 64 + ty * 4 + i) * 192 + ct + tx * 4 + j];
  }
  for (int i = 0; i < 4; ++i)
    for (int j = 0; j < 4; ++j)
      base[(ty * 4 + i) * 192 + tx * 4 + j] = acc[i][j];
}

// ----------------------------------------------------------------------------
// FFT forward over h (real -> complex), real in-place into xh, imag -> Si
// ----------------------------------------------------------------------------
__global__ __launch_bounds__(256) void ffth_kernel(
    float* xh, float* Si, const float2* E64, const int* sel)
{
  int b = blockIdx.y;
  if (sel[b] != 1) return;
  int q0 = blockIdx.x * 64;
  __shared__ float er[64][65], ei[64][65], xs[64][65];
  int t = threadIdx.x;
  for (int i = t; i < 4096; i += 256) {
    int r = i >> 6, c = i & 63;
    float2 e = E64[i];
    er[r][c] = e.x; ei[r][c] = e.y;
    xs[r][c] = xh[(size_t)b * SLICE + r * 12288 + q0 + c];
  }
  __syncthreads();
  int tx = t & 15, ty = t >> 4;
  float ar[4][4] = {}, ai[4][4] = {};
  for (int l = 0; l < 64; ++l) {
    float e1[4], e2[4], xv[4];
#pragma unroll
    for (int i = 0; i < 4; ++i) { e1[i] = er[l][ty * 4 + i]; e2[i] = ei[l][ty * 4 + i]; }
#pragma unroll
    for (int j = 0; j < 4; ++j) xv[j] = xs[l][tx * 4 + j];
#pragma unroll
    for (int i = 0; i < 4; ++i)
#pragma unroll
      for (int j = 0; j < 4; ++j) { ar[i][j] += e1[i] * xv[j]; ai[i][j] += e2[i] * xv[j]; }
  }
  size_t ob = (size_t)b * SLICE;
  for (int i = 0; i < 4; ++i)
    for (int j = 0; j < 4; ++j) {
      size_t o = ob + (size_t)(ty * 4 + i) * 12288 + q0 + tx * 4 + j;
      xh[o] = ar[i][j];
      Si[o] = ai[i][j];
    }
}

// FFT over w (complex, in-place). grid (384, 32)
__global__ __launch_bounds__(256) void fftw_kernel(
    float* Sr, float* Si, const float2* E64, const int* sel, float s)
{
  int b = blockIdx.y;
  if (sel[b] != 1) return;
  int kh = blockIdx.x / 6;
  int ct = (blockIdx.x - kh * 6) * 32;
  float* br = Sr + (size_t)b * SLICE + kh * 12288 + ct;
  float* bi = Si + (size_t)b * SLICE + kh * 12288 + ct;
  __shared__ float er[64][65], ei[64][65];
  __shared__ float xr[64][33], xi[64][33];
  int t = threadIdx.x;
  for (int i = t; i < 4096; i += 256) {
    float2 e = E64[i];
    er[i >> 6][i & 63] = e.x;
    ei[i >> 6][i & 63] = s * e.y;
  }
  for (int i = t; i < 2048; i += 256) {
    int l = i >> 5, q = i & 31;
    xr[l][q] = br[l * 192 + q];
    xi[l][q] = bi[l * 192 + q];
  }
  __syncthreads();
  int tx = t & 7, ty = t >> 3;
  float ar[2][4] = {}, ac[2][4] = {};
  for (int l = 0; l < 64; ++l) {
    float e1a = er[l][ty],      e2a = ei[l][ty];
    float e1b = er[l][ty + 32], e2b = ei[l][ty + 32];
#pragma unroll
    for (int j = 0; j < 4; ++j) {
      float vr = xr[l][tx * 4 + j], vi = xi[l][tx * 4 + j];
      ar[0][j] += e1a * vr - e2a * vi;
      ac[0][j] += e1a * vi + e2a * vr;
      ar[1][j] += e1b * vr - e2b * vi;
      ac[1][j] += e1b * vi + e2b * vr;
    }
  }
  for (int r = 0; r < 2; ++r) {
    int kw = ty + r * 32;
    for (int j = 0; j < 4; ++j) {
      br[kw * 192 + tx * 4 + j] = ar[r][j];
      bi[kw * 192 + tx * 4 + j] = ac[r][j];
    }
  }
}

// ----------------------------------------------------------------------------
// Fused c-stage: S <- ((S @ E192) * k*SCALE) @ conj(E192), in-place per 32-row
// tile. Register-rotator twiddles (zero LDS lookups, zero int ops in loop).
// Tiling: 256 thr = 4 row-groups(8 rows) x 64 freq-groups(3 freqs).
// grid (128, 32). LDS 52224 B (3 blocks/CU).
// ----------------------------------------------------------------------------
__global__ __launch_bounds__(256) void fftc_fused_kernel(
    float* Sr, float* Si, const float* kmap, const int* sel)
{
  int b = blockIdx.y;
  if (sel[b] != 1) return;
  int m0 = blockIdx.x * 32;
  float* br = Sr + (size_t)b * SLICE + (size_t)m0 * 192;
  float* bi = Si + (size_t)b * SLICE + (size_t)m0 * 192;
  __shared__ float Tr[192][34];   // [c or f][row], stride 34: 8B-aligned rows,
  __shared__ float Ti[192][34];   // 2-way bank aliasing only (free)
  int t = threadIdx.x;
  for (int i = t; i < 6144; i += 256) {
    int row = i / 192, c = i - row * 192;
    Tr[c][row] = br[i];
    Ti[c][row] = bi[i];
  }
  int tx = t & 63, ty = t >> 6;          // ty uniform per wave -> broadcast reads
  int rbase = ty * 8;
  // rotator step w^f for f = tx*3 + j  (w = e^{-2*pi*i/192})
  float sr[3], sj[3];
#pragma unroll
  for (int j = 0; j < 3; ++j) {
    double th = -2.0 * 3.14159265358979323846 * (double)(tx * 3 + j) / 192.0;
    sr[j] = (float)cos(th);
    sj[j] = (float)sin(th);
  }
  __syncthreads();
  // pass 1: F[row][f] = sum_k T[row][k] * w^{k f}
  float ar[8][3], ai[8][3];
#pragma unroll
  for (int r = 0; r < 8; ++r)
#pragma unroll
    for (int j = 0; j < 3; ++j) { ar[r][j] = 0.f; ai[r][j] = 0.f; }
  {
    float pr[3], pi[3];
#pragma unroll
    for (int j = 0; j < 3; ++j) { pr[j] = 1.f; pi[j] = 0.f; }
    for (int k = 0; k < 192; ++k) {
      float xr[8], xi[8];
#pragma unroll
      for (int r = 0; r < 8; ++r) { xr[r] = Tr[k][rbase + r]; xi[r] = Ti[k][rbase + r]; }
#pragma unroll
      for (int j = 0; j < 3; ++j) {
        float er = pr[j], ei = pi[j];
#pragma unroll
        for (int r = 0; r < 8; ++r) {
          ar[r][j] += xr[r] * er - xi[r] * ei;
          ai[r][j] += xr[r] * ei + xi[r] * er;
        }
        pr[j] = er * sr[j] - ei * sj[j];
        pi[j] = er * sj[j] + ei * sr[j];
      }
    }
  }
  const float SCALE = 1.0f / 786432.0f;
#pragma unroll
  for (int r = 0; r < 8; ++r)
#pragma unroll
    for (int j = 0; j < 3; ++j) {
      float kv = kmap[(size_t)(m0 + rbase + r) * 192 + tx * 3 + j] * SCALE;
      ar[r][j] *= kv; ai[r][j] *= kv;
    }
  __syncthreads();
#pragma unroll
  for (int r = 0; r < 8; ++r)
#pragma unroll
    for (int j = 0; j < 3; ++j) {
      Tr[tx * 3 + j][rbase + r] = ar[r][j];
      Ti[tx * 3 + j][rbase + r] = ai[r][j];
    }
  __syncthreads();
  // pass 2: out[row][c] = sum_f G[row][f] * e^{+2*pi*i*f*c/192}
  // rotator p advances by e^{+2*pi*i*c/192} = (sr[j], -sj[j])
  float qr[8][3], qi[8][3];
#pragma unroll
  for (int r = 0; r < 8; ++r)
#pragma unroll
    for (int j = 0; j < 3; ++j) { qr[r][j] = 0.f; qi[r][j] = 0.f; }
  {
    float pr[3], pi[3];
#pragma unroll
    for (int j = 0; j < 3; ++j) { pr[j] = 1.f; pi[j] = 0.f; }
    for (int k = 0; k < 192; ++k) {
      float xr[8], xi[8];
#pragma unroll
      for (int r = 0; r < 8; ++r) { xr[r] = Tr[k][rbase + r]; xi[r] = Ti[k][rbase + r]; }
#pragma unroll
      for (int j = 0; j < 3; ++j) {
        float er = pr[j], ei = pi[j];
#pragma unroll
        for (int r = 0; r < 8; ++r) {
          qr[r][j] += xr[r] * er - xi[r] * ei;
          qi[r][j] += xr[r] * ei + xi[r] * er;
        }
        pr[j] = er * sr[j] + ei * sj[j];   // conj step
        pi[j] = ei * sr[j] - er * sj[j];
      }
    }
  }
#pragma unroll
  for (int r = 0; r < 8; ++r)
#pragma unroll
    for (int j = 0; j < 3; ++j) {
      br[(rbase + r) * 192 + tx * 3 + j] = qr[r][j];
      bi[(rbase + r) * 192 + tx * 3 + j] = qi[r][j];
    }
}

// inverse h-stage, real part only, in-place into xh. grid (384, 32)
__global__ __launch_bounds__(256) void ffthi_kernel(
    float* Sr, const float* Si, const float2* E64, const int* sel)
{
  int b = blockIdx.y;
  if (sel[b] != 1) return;
  int q0 = blockIdx.x * 32;
  __shared__ float er[64][65], ei[64][65];
  __shared__ float xr[64][33], xi[64][33];
  int t = threadIdx.x;
  for (int i = t; i < 4096; i += 256) {
    float2 e = E64[i];
    er[i >> 6][i & 63] = e.x;
    ei[i >> 6][i & 63] = e.y;
  }
  for (int i = t; i < 2048; i += 256) {
    int l = i >> 5, q = i & 31;
    size_t o = (size_t)b * SLICE + (size_t)l * 12288 + q0 + q;
    xr[l][q] = Sr[o];
    xi[l][q] = Si[o];
  }
  __syncthreads();
  int tx = t & 7, ty = t >> 3;
  float acc[2][4] = {};
  for (int l = 0; l < 64; ++l) {
    float e1a = er[l][ty],      e2a = ei[l][ty];
    float e1b = er[l][ty + 32], e2b = ei[l][ty + 32];
#pragma unroll
    for (int j = 0; j < 4; ++j) {
      float vr = xr[l][tx * 4 + j], vi = xi[l][tx * 4 + j];
      acc[0][j] += e1a * vr + e2a * vi;   // Re(e^{+i th} A), ei = -sin
      acc[1][j] += e1b * vr + e2b * vi;
    }
  }
  for (int r = 0; r < 2; ++r) {
    int h = ty + r * 32;
    for (int j = 0; j < 4; ++j)
      Sr[(size_t)b * SLICE + (size_t)h * 12288 + q0 + tx * 4 + j] = acc[r][j];
  }
}

// ----------------------------------------------------------------------------
// Haar branch, in-place on xh (haar along C: 64-chunks then full 192)
// grid (128, 32)
// ----------------------------------------------------------------------------
__global__ __launch_bounds__(256) void haar_kernel(
    float* xh, const float* kmap, const int* sel)
{
  int b = blockIdx.y;
  if (sel[b] != 2) return;
  int h = blockIdx.x >> 1;
  int w0 = (blockIdx.x & 1) * 32;
  size_t base = (size_t)b * SLICE + ((size_t)h * 64 + w0) * 192;
  __shared__ float A[32 * 192];
  __shared__ float Bf[32 * 192];
  int t = threadIdx.x;
  for (int i = t; i < 6144; i += 256) A[i] = xh[base + i];
  __syncthreads();
  for (int u = t; u < 32 * 96; u += 256) {
    int p = u / 96, r = u - p * 96;
    int ch = r >> 5, i = r & 31;
    float v0 = A[p * 192 + ch * 64 + 2 * i];
    float v1 = A[p * 192 + ch * 64 + 2 * i + 1];
    Bf[p * 192 + ch * 64 + i]      = (v0 + v1) * 0.5f;
    Bf[p * 192 + ch * 64 + 32 + i] = (v0 - v1) * 0.5f;
  }
  __syncthreads();
  for (int u = t; u < 32 * 96; u += 256) {
    int p = u / 96, i = u - p * 96;
    float v0 = Bf[p * 192 + 2 * i];
    float v1 = Bf[p * 192 + 2 * i + 1];
    A[p * 192 + i]      = (v0 + v1) * 0.5f;
    A[p * 192 + 96 + i] = (v0 - v1) * 0.5f;
  }
  __syncthreads();
  for (int i = t; i < 6144; i += 256)
    A[i] *= kmap[((size_t)h * 64 + w0) * 192 + i];
  __syncthreads();
  for (int u = t; u < 32 * 96; u += 256) {
    int p = u / 96, r = u - p * 96;
    int ch = r >> 5, i = r & 31;
    float a = A[p * 192 + ch * 64 + i];
    float d = A[p * 192 + ch * 64 + 32 + i];
    Bf[p * 192 + ch * 64 + 2 * i]     = a + d;
    Bf[p * 192 + ch * 64 + 2 * i + 1] = a - d;
  }
  __syncthreads();
  for (int u = t; u < 32 * 96; u += 256) {
    int p = u / 96, i = u - p * 96;
    float a = Bf[p * 192 + i];
    float d = Bf[p * 192 + 96 + i];
    A[p * 192 + 2 * i]     = a + d;
    A[p * 192 + 2 * i + 1] = a - d;
  }
  __syncthreads();
  for (int i = t; i < 6144; i += 256) xh[base + i] = A[i];
}

// ----------------------------------------------------------------------------
// final: LN(c) * silu(z) @ out_w^T + out_b, dual-dtype store. grid 2048
// ----------------------------------------------------------------------------
__global__ __launch_bounds__(256) void final_kernel(
    const float* comb, const bf16* zb, const float* lng, const float* lnb,
    const float* wT, const float* outb, void* outp, const int* flag)
{
  int flg = *flag;
  int bi = blockIdx.x;
  int b = bi >> 6, h = bi & 63;
  size_t base = ((size_t)b * 4096 + (size_t)h * 64) * 192;
  __shared__ float As[64 * 194];
  __shared__ float mu[64], rs[64];
  int t = threadIdx.x;
  for (int e = t; e < 12288; e += 256) {
    int p = e / 192, c = e - p * 192;
    As[p * 194 + c] = scrub(comb[base + e]);
  }
  __syncthreads();
  if (t < 64) {
    float s = 0.f;
    for (int c = 0; c < 192; ++c) s += As[t * 194 + c];
    float m = s * (1.f / 192.f);
    float v = 0.f;
    for (int c = 0; c < 192; ++c) { float d = As[t * 194 + c] - m; v += d * d; }
    v *= (1.f / 192.f);
    mu[t] = m;
    rs[t] = 1.f / sqrtf(v + 1e-5f);
  }
  __syncthreads();
  for (int e = t; e < 12288; e += 256) {
    int p = e / 192, c = e - p * 192;
    float v = (As[p * 194 + c] - mu[p]) * rs[p] * lng[c] + lnb[c];
    float zv = scrub(b2f(zb[base + e]));
    v *= zv / (1.f + expf(-zv));
    As[p * 194 + c] = v;
  }
  __syncthreads();
  int tx = t & 15, ty = t >> 4;
  float acc[4][12];
  for (int i = 0; i < 4; ++i)
    for (int j = 0; j < 12; ++j) acc[i][j] = 0.f;
  for (int c = 0; c < 192; ++c) {
    float av[4];
#pragma unroll
    for (int i = 0; i < 4; ++i) av[i] = As[(ty * 4 + i) * 194 + c];
    float wv[12];
#pragma unroll
    for (int j = 0; j < 12; ++j) wv[j] = wT[(size_t)c * 192 + tx * 12 + j];
#pragma unroll
    for (int i = 0; i < 4; ++i)
#pragma unroll
      for (int j = 0; j < 12; ++j) acc[i][j] += av[i] * wv[j];
  }
  __syncthreads();
  for (int i = 0; i < 4; ++i)
    for (int j = 0; j < 12; ++j) {
      int co = tx * 12 + j, p = ty * 4 + i;
      As[co * 64 + p] = acc[i][j] + outb[co];
    }
  __syncthreads();
  for (int e = t; e < 12288; e += 256) {
    int co = e >> 6, w = e & 63;
    size_t oi = (((size_t)b * 192 + co) * 64 + h) * 64 + w;
    if (flg) ((float*)outp)[oi] = As[e];
    else     ((bf16*)outp)[oi] = __float2bfloat16(As[e]);
  }
}

// ----------------------------------------------------------------------------
extern "C" void kernel_launch(void* const* d_in, const int* in_sizes, int n_in,
                              void* d_out, int out_size, void* d_ws, size_t ws_size,
                              hipStream_t stream) {
  (void)in_sizes; (void)n_in;
  if (ws_size < WS_NEEDED_BYTES) {
    fill_zero_kernel<<<(out_size + 255) / 256, 256, 0, stream>>>(
        (unsigned short*)d_out, out_size);
    return;
  }
  float* ws    = (float*)d_ws;
  float* xh    = ws + O_XH;
  float* Si    = ws + O_SI;
  bf16*  zb    = (bf16*)(ws + O_ZB);
  float* kmap  = ws + O_KMAP;
  float2* E64  = (float2*)(ws + O_E64);
  float* Dm    = ws + O_DM;
  float* DT    = ws + O_DT;
  float* wT    = ws + O_WT;
  float* pooled= ws + O_POOL;
  int*   sel   = (int*)(ws + O_SEL);
  int*   flag  = (int*)(ws + O_FLAG);

  sniff_kernel<<<1, 64, 0, stream>>>((const unsigned short*)d_in[0], flag);

  CvtArgs ca;
  const int srcidx[22] = {2,3,4,5,6,7,8,9,10,11,12,13,14,15,16,17,18,19,20,21,22,1};
  const int ns[22] = {96,1728,192,73728,384,49152,256,256,256,8192,32,32,32,96,3,
                      36864,192,192,192,36864,192,786432};
  const long long offs[22] = {
    (long long)W_GN,(long long)W_DWW,(long long)W_DWB,(long long)W_LINW,
    (long long)W_LINB,(long long)W_P1W,(long long)W_P1B,(long long)W_G1,
    (long long)W_B1,(long long)W_P2W,(long long)W_P2B,(long long)W_G2,
    (long long)W_B2,(long long)W_P3W,(long long)W_P3B,(long long)W_TOKW,
    (long long)W_TOKB,(long long)W_LNG,(long long)W_LNB,(long long)W_OUTW,
    (long long)W_OUTB,(long long)O_FREQ};
  for (int i = 0; i < 22; ++i) { ca.src[i] = d_in[srcidx[i]]; ca.n[i] = ns[i]; ca.off[i] = offs[i]; }
  cvt_kernel<<<64, 256, 0, stream>>>(ca, ws, flag);

  setup_kernel<<<64, 256, 0, stream>>>(Dm, DT, E64, wT, ws + W_OUTW);
  conv_kernel<<<dim3(6, 64, 32), 256, 0, stream>>>(d_in[0], flag, ws + W_DWW, ws + W_DWB, Si);
  linear_kernel<<<dim3(2048, 6), 256, 0, stream>>>(Si, ws + W_LINW, ws + W_LINB, xh, zb);
  pool_kernel<<<dim3(12, 32), 256, 0, stream>>>(xh, pooled);
  mlp_kernel<<<1, 256, 0, stream>>>(pooled, ws + W_GN,
      ws + W_P1W, ws + W_P1B, ws + W_G1, ws + W_B1,
      ws + W_P2W, ws + W_P2B, ws + W_G2, ws + W_B2,
      ws + W_P3W, ws + W_P3B, sel);
  kmap_kernel<<<dim3(64, 3), 256, 0, stream>>>(ws + O_FREQ, ws + W_TOKW, ws + W_TOKB, kmap);
  // DCT branch (sel==0), in-place on xh
  axis0_kernel<<<dim3(192, 32), 256, 0, stream>>>(xh, Dm, sel, 0);
  axis1_kernel<<<dim3(192, 32), 256, 0, stream>>>(xh, Dm, kmap, sel, 0);
  axis1_kernel<<<dim3(192, 32), 256, 0, stream>>>(xh, DT, nullptr, sel, 0);
  axis0_kernel<<<dim3(192, 32), 256, 0, stream>>>(xh, DT, sel, 0);
  // FFT branch (sel==1); b-axis FFT/IFFT cancels analytically; in-place (xh,Si)
  ffth_kernel<<<dim3(192, 32), 256, 0, stream>>>(xh, Si, E64, sel);
  fftw_kernel<<<dim3(384, 32), 256, 0, stream>>>(xh, Si, E64, sel, 1.f);
  fftc_fused_kernel<<<dim3(128, 32), 256, 0, stream>>>(xh, Si, kmap, sel);
  fftw_kernel<<<dim3(384, 32), 256, 0, stream>>>(xh, Si, E64, sel, -1.f);
  ffthi_kernel<<<dim3(384, 32), 256, 0, stream>>>(xh, Si, E64, sel);
  // Haar branch (sel==2), in-place on xh
  haar_kernel<<<dim3(128, 32), 256, 0, stream>>>(xh, kmap, sel);
  // epilogue
  final_kernel<<<2048, 256, 0, stream>>>(xh, zb, ws + W_LNG, ws + W_LNB,
                                         wT, ws + W_OUTB, d_out, flag);
}